// Round 1
// baseline (339.607 us; speedup 1.0000x reference)
//
#include <hip/hip_runtime.h>
#include <hip/hip_bf16.h>

typedef unsigned short u16;

#define B_   128
#define PP_  1024
#define LP_  128
#define H_   256
#define NP_  131072
#define NL_  16384
#define M_   147456
#define BM_  64
#define WPAD 40    // u16 per weight-tile row: 32 data + 8 pad (80B stride -> 2-way LDS aliasing, free)
#define Y1S  264   // u16 per y1 row: 256 data + 8 pad (528B stride -> 2-way)

typedef __bf16 bf16x8 __attribute__((ext_vector_type(8)));
typedef float  f32x4  __attribute__((ext_vector_type(4)));

__device__ __forceinline__ u16 f2bf(float f) {
  __hip_bfloat16 h = __float2bfloat16(f);
  return __builtin_bit_cast(u16, h);
}

// ---------------------------------------------------------------- weights prep
// w1t[n*256+k] = bf16(Wd1[k*256+n]); same for Wd2. Tiled transpose, coalesced both sides.
__global__ void __launch_bounds__(256) prep_weights_k(
    const float* __restrict__ W1, const float* __restrict__ W2,
    u16* __restrict__ w1t, u16* __restrict__ w2t)
{
  __shared__ float t1[32][33];
  __shared__ float t2[32][33];
  const int bx = (blockIdx.x & 7) * 32;   // n tile
  const int by = (blockIdx.x >> 3) * 32;  // k tile
  const int lx = threadIdx.x & 31;
  const int ly = threadIdx.x >> 5;        // 0..7
#pragma unroll
  for (int r = 0; r < 32; r += 8) {
    t1[ly + r][lx] = W1[(by + ly + r) * 256 + bx + lx];
    t2[ly + r][lx] = W2[(by + ly + r) * 256 + bx + lx];
  }
  __syncthreads();
#pragma unroll
  for (int r = 0; r < 32; r += 8) {
    const int n = bx + ly + r;
    w1t[n * 256 + by + lx] = f2bf(t1[lx][ly + r]);
    w2t[n * 256 + by + lx] = f2bf(t2[lx][ly + r]);
  }
}

// ---------------------------------------------------------------- fused embed+MLP+pool
// One block = 64 rows (batch-uniform). 4 waves, each wave owns 16 rows x all 256 cols.
// GEMM1: gather embeddings straight into A-frags, Wd1^T staged in LDS, silu -> y1 (LDS, bf16).
// GEMM2: y1 @ Wd2, epilogue = per-wave column sums -> atomicAdd into pool[batch][col].
__global__ void __launch_bounds__(256) mlp_pool_k(
    const int* __restrict__ pel, const int* __restrict__ paa,
    const int* __restrict__ pbb, const int* __restrict__ ltyp,
    const float* __restrict__ Ee, const float* __restrict__ Ea,
    const float* __restrict__ Eb, const float* __restrict__ El,
    const u16* __restrict__ w1t, const u16* __restrict__ w2t,
    const float* __restrict__ bd1,
    float* __restrict__ poolP, float* __restrict__ poolL)
{
  __shared__ __attribute__((aligned(16))) u16 wtile[256 * WPAD];  // 20480 B
  __shared__ __attribute__((aligned(16))) u16 y1s[BM_ * Y1S];     // 33792 B

  const int tid  = threadIdx.x;
  const int wave = tid >> 6;
  const int lane = tid & 63;
  const int l15  = lane & 15;
  const int quad = lane >> 4;
  const int row0 = blockIdx.x * BM_;
  const bool isProt = row0 < NP_;
  const int myrow = row0 + wave * 16 + l15;

  const float* g0;
  const float* g1 = nullptr;
  const float* g2 = nullptr;
  if (isProt) {
    g0 = Ee + pel[myrow] * H_;
    g1 = Ea + paa[myrow] * H_;
    g2 = Eb + pbb[myrow] * H_;
  } else {
    g0 = El + ltyp[myrow - NP_] * H_;
  }

  f32x4 acc[16];
#pragma unroll
  for (int t = 0; t < 16; ++t) acc[t] = (f32x4){0.f, 0.f, 0.f, 0.f};

  // ---- GEMM1: h @ Wd1 ----
#pragma unroll 1
  for (int ks = 0; ks < 8; ++ks) {
    // prefetch weight tile to regs (n = tid, 32 k's = 64B)
    const int4* wsrc = (const int4*)(w1t + tid * 256 + ks * 32);
    int4 w0 = wsrc[0], w1 = wsrc[1], w2 = wsrc[2], w3 = wsrc[3];

    // gather A-frag: h[myrow][ks*32 + quad*8 + j], j=0..7
    const int koff = ks * 32 + quad * 8;
    float hv[8];
    if (isProt) {
      const float4* p0 = (const float4*)(g0 + koff);
      const float4* p1 = (const float4*)(g1 + koff);
      const float4* p2 = (const float4*)(g2 + koff);
      float4 a0 = p0[0], a1 = p0[1];
      float4 b0 = p1[0], b1 = p1[1];
      float4 c0 = p2[0], c1 = p2[1];
      hv[0] = a0.x + b0.x + c0.x; hv[1] = a0.y + b0.y + c0.y;
      hv[2] = a0.z + b0.z + c0.z; hv[3] = a0.w + b0.w + c0.w;
      hv[4] = a1.x + b1.x + c1.x; hv[5] = a1.y + b1.y + c1.y;
      hv[6] = a1.z + b1.z + c1.z; hv[7] = a1.w + b1.w + c1.w;
    } else {
      const float4* p0 = (const float4*)(g0 + koff);
      float4 a0 = p0[0], a1 = p0[1];
      hv[0] = a0.x; hv[1] = a0.y; hv[2] = a0.z; hv[3] = a0.w;
      hv[4] = a1.x; hv[5] = a1.y; hv[6] = a1.z; hv[7] = a1.w;
    }
    union { bf16x8 v; u16 u[8]; } af;
#pragma unroll
    for (int j = 0; j < 8; ++j) af.u[j] = f2bf(hv[j]);

    __syncthreads();   // prev iter's wtile reads complete
    {
      int4* wdst = (int4*)&wtile[tid * WPAD];
      wdst[0] = w0; wdst[1] = w1; wdst[2] = w2; wdst[3] = w3;
    }
    __syncthreads();   // tile staged

#pragma unroll
    for (int t = 0; t < 16; ++t) {
      bf16x8 bf = *(const bf16x8*)&wtile[(t * 16 + l15) * WPAD + quad * 8];
      acc[t] = __builtin_amdgcn_mfma_f32_16x16x32_bf16(af.v, bf, acc[t], 0, 0, 0);
    }
  }

  // ---- epilogue 1: +bd1, silu, -> y1s (bf16) ----
#pragma unroll
  for (int t = 0; t < 16; ++t) {
    const int n = t * 16 + l15;
    const float bias = bd1[n];
#pragma unroll
    for (int r = 0; r < 4; ++r) {
      float v = acc[t][r] + bias;
      float s = v / (1.f + __expf(-v));
      const int row = wave * 16 + quad * 4 + r;
      y1s[row * Y1S + n] = f2bf(s);
    }
    acc[t] = (f32x4){0.f, 0.f, 0.f, 0.f};
  }
  // y1s visibility handled by the leading __syncthreads of GEMM2's first iteration.

  // ---- GEMM2: y1 @ Wd2 ----
#pragma unroll 1
  for (int ks = 0; ks < 8; ++ks) {
    const int4* wsrc = (const int4*)(w2t + tid * 256 + ks * 32);
    int4 w0 = wsrc[0], w1 = wsrc[1], w2 = wsrc[2], w3 = wsrc[3];
    __syncthreads();
    {
      int4* wdst = (int4*)&wtile[tid * WPAD];
      wdst[0] = w0; wdst[1] = w1; wdst[2] = w2; wdst[3] = w3;
    }
    __syncthreads();
    bf16x8 af2 = *(const bf16x8*)&y1s[(wave * 16 + l15) * Y1S + ks * 32 + quad * 8];
#pragma unroll
    for (int t = 0; t < 16; ++t) {
      bf16x8 bf = *(const bf16x8*)&wtile[(t * 16 + l15) * WPAD + quad * 8];
      acc[t] = __builtin_amdgcn_mfma_f32_16x16x32_bf16(af2, bf, acc[t], 0, 0, 0);
    }
  }

  // ---- pooling epilogue: column sums over this wave's 16 rows, atomic into pool ----
  float* pool = isProt ? poolP : poolL;
  const int batch = isProt ? (row0 >> 10) : ((row0 - NP_) >> 7);
#pragma unroll
  for (int t = 0; t < 16; ++t) {
    float v = acc[t][0] + acc[t][1] + acc[t][2] + acc[t][3];
    v += __shfl_xor(v, 16);
    v += __shfl_xor(v, 32);
    if (lane < 16) atomicAdd(&pool[batch * H_ + t * 16 + lane], v);
  }
}

// ---------------------------------------------------------------- contact features
// One block per batch. min over proteins of dist(lig, prot), then mean/min over ligands.
__global__ void __launch_bounds__(256) contact_k(
    const float* __restrict__ ppos, const float* __restrict__ lpos,
    float* __restrict__ contact)
{
  __shared__ float px[PP_], py[PP_], pz[PP_];
  __shared__ float lmin[LP_];
  const int b = blockIdx.x;
  const int tid = threadIdx.x;
  for (int i = tid; i < PP_; i += 256) {
    const float* p = ppos + (size_t)(b * PP_ + i) * 3;
    px[i] = p[0]; py[i] = p[1]; pz[i] = p[2];
  }
  __syncthreads();
  const int lig = tid >> 1, half = tid & 1;
  const float* lp = lpos + (size_t)(b * LP_ + lig) * 3;
  const float lx = lp[0], ly = lp[1], lz = lp[2];
  float m = 1e30f;
  const int j0 = half * 512;
#pragma unroll 4
  for (int j = j0; j < j0 + 512; ++j) {
    float dx = lx - px[j], dy = ly - py[j], dz = lz - pz[j];
    float d2 = dx * dx + dy * dy + dz * dz;
    m = fminf(m, d2);
  }
  m = fminf(m, __shfl_xor(m, 1));
  if (half == 0) lmin[lig] = sqrtf(m);
  __syncthreads();
  if (tid < 64) {
    float a = lmin[tid], c = lmin[tid + 64];
    float s = a + c;
    float mn = fminf(a, c);
#pragma unroll
    for (int off = 32; off; off >>= 1) {
      s += __shfl_down(s, off);
      mn = fminf(mn, __shfl_down(mn, off));
    }
    if (tid == 0) {
      contact[b * 2 + 0] = s * (1.f / (float)LP_);
      contact[b * 2 + 1] = mn;
    }
  }
}

// ---------------------------------------------------------------- final MLP
// One block per batch; thread j = hidden unit j. bd2 folded into pooled mean here.
__global__ void __launch_bounds__(256) final_k(
    const float* __restrict__ poolP, const float* __restrict__ poolL,
    const float* __restrict__ contact, const float* __restrict__ bd2,
    const float* __restrict__ Wa1, const float* __restrict__ ba1,
    const float* __restrict__ Wa2, const float* __restrict__ ba2,
    float* __restrict__ out)
{
  __shared__ float gf[2 * H_ + 2];
  __shared__ float red[4];
  const int b = blockIdx.x;
  const int tid = threadIdx.x;
  gf[tid]        = poolP[b * H_ + tid] * (1.f / (float)PP_) + bd2[tid];
  gf[H_ + tid]   = poolL[b * H_ + tid] * (1.f / (float)LP_) + bd2[tid];
  if (tid == 0) {
    gf[2 * H_ + 0] = contact[b * 2 + 0];
    gf[2 * H_ + 1] = contact[b * 2 + 1];
  }
  __syncthreads();
  float a = ba1[tid];
#pragma unroll 2
  for (int i = 0; i < 2 * H_ + 2; ++i) a += gf[i] * Wa1[i * H_ + tid];
  float s = a / (1.f + __expf(-a));
  float p = s * Wa2[tid];
#pragma unroll
  for (int off = 32; off; off >>= 1) p += __shfl_down(p, off);
  if ((tid & 63) == 0) red[tid >> 6] = p;
  __syncthreads();
  if (tid == 0) out[b] = red[0] + red[1] + red[2] + red[3] + ba2[0];
}

// ---------------------------------------------------------------- launch
extern "C" void kernel_launch(void* const* d_in, const int* in_sizes, int n_in,
                              void* d_out, int out_size, void* d_ws, size_t ws_size,
                              hipStream_t stream)
{
  const float* protein_pos = (const float*)d_in[0];
  const float* ligand_pos  = (const float*)d_in[1];
  const int*   pel  = (const int*)d_in[2];
  const int*   paa  = (const int*)d_in[3];
  const int*   pbb  = (const int*)d_in[4];
  const int*   ltyp = (const int*)d_in[5];
  // d_in[6], d_in[7]: batch index arrays (repeat(arange(B))) — implied by block layout
  const float* Ee  = (const float*)d_in[8];
  const float* Ea  = (const float*)d_in[9];
  const float* Eb  = (const float*)d_in[10];
  const float* El  = (const float*)d_in[11];
  const float* Wd1 = (const float*)d_in[12];
  const float* bd1 = (const float*)d_in[13];
  const float* Wd2 = (const float*)d_in[14];
  const float* bd2 = (const float*)d_in[15];
  const float* Wa1 = (const float*)d_in[16];
  const float* ba1 = (const float*)d_in[17];
  const float* Wa2 = (const float*)d_in[18];
  const float* ba2 = (const float*)d_in[19];
  float* out = (float*)d_out;

  char* ws = (char*)d_ws;
  u16*   w1t     = (u16*)(ws);               // 131072 B
  u16*   w2t     = (u16*)(ws + 131072);      // 131072 B
  float* poolP   = (float*)(ws + 262144);    // 131072 B
  float* poolL   = (float*)(ws + 393216);    // 131072 B
  float* contact = (float*)(ws + 524288);    // 1024 B

  hipMemsetAsync(poolP, 0, 2 * B_ * H_ * sizeof(float), stream);  // zero both pools
  prep_weights_k<<<64, 256, 0, stream>>>(Wd1, Wd2, w1t, w2t);
  mlp_pool_k<<<M_ / BM_, 256, 0, stream>>>(pel, paa, pbb, ltyp, Ee, Ea, Eb, El,
                                           w1t, w2t, bd1, poolP, poolL);
  contact_k<<<B_, 256, 0, stream>>>(protein_pos, ligand_pos, contact);
  final_k<<<B_, 256, 0, stream>>>(poolP, poolL, contact, bd2,
                                  Wa1, ba1, Wa2, ba2, out);
}

// Round 2
// 190.972 us; speedup vs baseline: 1.7783x; 1.7783x over previous
//
#include <hip/hip_runtime.h>
#include <hip/hip_bf16.h>

typedef unsigned short u16;
typedef _Float16 f16;
typedef _Float16 h8 __attribute__((ext_vector_type(8)));
typedef float f32x4 __attribute__((ext_vector_type(4)));

#define B_   128
#define PP_  1024
#define LP_  128
#define H_   256
#define NP_  131072
#define NL_  16384
#define NT_  4608      // (131072 + 16384) / 32 row-tiles
#define GRID_MLP 512
#define ASTRIDE 264    // 256 + 8 pad (f16 units)

// ---------------------------------------------------------------- prep
// grid 256: every block zeros its slice of ysum (2*128*256 floats);
// blocks 0..63 transpose W1 -> f16 w1t[n*256+k]; blocks 64..241 convert tables.
__global__ void __launch_bounds__(256) prep_k(
    const float* __restrict__ W1,
    const float* __restrict__ Ee, const float* __restrict__ Ea,
    const float* __restrict__ Eb, const float* __restrict__ El,
    f16* __restrict__ w1t, f16* __restrict__ tbl, float* __restrict__ ysum)
{
  __shared__ float t1[32][33];
  const int bid = blockIdx.x, tid = threadIdx.x;
  ysum[bid * 256 + tid] = 0.f;
  if (bid < 64) {
    const int bx = (bid & 7) * 32, by = (bid >> 3) * 32;
    const int lx = tid & 31, ly = tid >> 5;
#pragma unroll
    for (int r = 0; r < 32; r += 8)
      t1[ly + r][lx] = W1[(by + ly + r) * 256 + bx + lx];
    __syncthreads();
#pragma unroll
    for (int r = 0; r < 32; r += 8)
      w1t[(bx + ly + r) * 256 + by + lx] = (f16)t1[lx][ly + r];
  } else if (bid < 242) {
    const int idx = (bid - 64) * 256 + tid;   // 178 blocks cover exactly 45568
    float v;
    if (idx < 32768)      v = Ee[idx];
    else if (idx < 40960) v = Ea[idx - 32768];
    else if (idx < 41472) v = Eb[idx - 40960];
    else                  v = El[idx - 41472];
    tbl[idx] = (f16)v;
  }
}

// ---------------------------------------------------------------- GEMM1 + silu + batch colsum
// Block = 256 threads = 4 waves; wave w owns cols [w*64, w*64+64) with its full-K
// W1^T slice resident in 128 VGPRs. Grid-stride over 32-row m-tiles: cooperatively
// gather+sum embeddings (f16) into LDS, each wave MFMAs its n-slice, then
// silu + column-sum + atomicAdd into per-batch pools.
__global__ void __launch_bounds__(256, 2) mlp1pool_k(
    const int* __restrict__ pel, const int* __restrict__ paa,
    const int* __restrict__ pbb, const int* __restrict__ ltyp,
    const f16* __restrict__ tbl, const f16* __restrict__ w1t,
    const float* __restrict__ bd1, float* __restrict__ ysum)
{
  __shared__ __attribute__((aligned(16))) f16 ldsA[32 * ASTRIDE];  // 16.5 KB
  const f16* Te = tbl;
  const f16* Ta = tbl + 32768;
  const f16* Tb = tbl + 40960;
  const f16* Tl = tbl + 41472;

  const int tid = threadIdx.x;
  const int wave = tid >> 6, lane = tid & 63;
  const int l15 = lane & 15, quad = lane >> 4;
  const int n0 = wave * 64;
  const int srow = tid >> 3, scp = tid & 7;  // staging: 8 threads/row, 32 k each

  // resident weights: 32 frags x 16 B = 128 VGPRs
  h8 Breg[32];
#pragma unroll
  for (int t = 0; t < 4; ++t)
#pragma unroll
    for (int ks = 0; ks < 8; ++ks)
      Breg[t * 8 + ks] = *(const h8*)(w1t + (n0 + t * 16 + l15) * 256 + ks * 32 + quad * 8);

  float bias[4];
#pragma unroll
  for (int t = 0; t < 4; ++t) bias[t] = bd1[n0 + t * 16 + l15];

  f32x4 acc[8];
#pragma unroll
  for (int i = 0; i < 8; ++i) acc[i] = (f32x4){0.f, 0.f, 0.f, 0.f};

  for (int T = blockIdx.x; T < NT_; T += GRID_MLP) {
    const bool prot = T < 4096;
    // gather this thread's 32-k slice of its row (sum of 3 tables for protein)
    h8 v[4];
    if (prot) {
      const int grow = T * 32 + srow;
      const h8* s0 = (const h8*)(Te + pel[grow] * 256 + scp * 32);
      const h8* s1 = (const h8*)(Ta + paa[grow] * 256 + scp * 32);
      const h8* s2 = (const h8*)(Tb + pbb[grow] * 256 + scp * 32);
#pragma unroll
      for (int c = 0; c < 4; ++c) v[c] = s0[c] + s1[c] + s2[c];
    } else {
      const int lrow = (T - 4096) * 32 + srow;
      const h8* s0 = (const h8*)(Tl + ltyp[lrow] * 256 + scp * 32);
#pragma unroll
      for (int c = 0; c < 4; ++c) v[c] = s0[c];
    }
    __syncthreads();   // previous tile's LDS reads complete
#pragma unroll
    for (int c = 0; c < 4; ++c)
      *(h8*)(ldsA + srow * ASTRIDE + scp * 32 + c * 8) = v[c];
    __syncthreads();   // tile staged

#pragma unroll
    for (int ks = 0; ks < 8; ++ks) {
      h8 a0 = *(const h8*)(ldsA + l15 * ASTRIDE + ks * 32 + quad * 8);
      h8 a1 = *(const h8*)(ldsA + (16 + l15) * ASTRIDE + ks * 32 + quad * 8);
#pragma unroll
      for (int t = 0; t < 4; ++t) {
        acc[t]     = __builtin_amdgcn_mfma_f32_16x16x32_f16(a0, Breg[t * 8 + ks], acc[t], 0, 0, 0);
        acc[4 + t] = __builtin_amdgcn_mfma_f32_16x16x32_f16(a1, Breg[t * 8 + ks], acc[4 + t], 0, 0, 0);
      }
    }

    // epilogue: silu + column sum over this tile's 32 rows -> atomic pool add
    const int batch = prot ? (T >> 5) : ((T - 4096) >> 2);
    float* pool = ysum + (prot ? 0 : 32768) + batch * 256;
#pragma unroll
    for (int t = 0; t < 4; ++t) {
      float s = 0.f;
#pragma unroll
      for (int mi = 0; mi < 2; ++mi)
#pragma unroll
        for (int r = 0; r < 4; ++r) {
          float pre = acc[mi * 4 + t][r] + bias[t];
          s += pre * __builtin_amdgcn_rcpf(1.f + __expf(-pre));
        }
      s += __shfl_xor(s, 16);
      s += __shfl_xor(s, 32);
      if (lane < 16) atomicAdd(pool + n0 + t * 16 + lane, s);
      acc[t] = (f32x4){0.f, 0.f, 0.f, 0.f};
      acc[4 + t] = (f32x4){0.f, 0.f, 0.f, 0.f};
    }
  }
}

// ---------------------------------------------------------------- contact + pooled GEMM2 + affinity
// One block per batch. Contact: thread = (ligand, protein-half), protein points via
// wave-uniform loads (scalar path). Then pooled = (ysum/cnt)@W2 + bd2 (fp32),
// gf = [pooledP, pooledL, contact], out = silu(gf@Wa1+ba1)@Wa2 + ba2.
__global__ void __launch_bounds__(256) final_k(
    const float* __restrict__ ppos, const float* __restrict__ lpos,
    const float* __restrict__ ysum, const float* __restrict__ W2,
    const float* __restrict__ bd2, const float* __restrict__ Wa1,
    const float* __restrict__ ba1, const float* __restrict__ Wa2,
    const float* __restrict__ ba2, float* __restrict__ out)
{
  __shared__ float ysP[256], ysL[256], d2s[256], red[8];
  __shared__ float gf[516];
  const int b = blockIdx.x, tid = threadIdx.x;

  // --- contact: min_j dist2(lig, prot_j) over this thread's half of proteins
  const int lig = tid & 127, half = tid >> 7;   // half is wave-uniform
  const float* lp = lpos + (size_t)(b * LP_ + lig) * 3;
  const float lx = lp[0], ly = lp[1], lz = lp[2];
  const float4* pb = (const float4*)(ppos + (size_t)(b * PP_ + half * 512) * 3);
  float m = 3.4e38f;
#pragma unroll 4
  for (int j = 0; j < 128; ++j) {
    float4 q0 = pb[j * 3], q1 = pb[j * 3 + 1], q2 = pb[j * 3 + 2];
    float dx, dy, dz, d2;
    dx = lx - q0.x; dy = ly - q0.y; dz = lz - q0.z;
    d2 = dx * dx + dy * dy + dz * dz; m = fminf(m, d2);
    dx = lx - q0.w; dy = ly - q1.x; dz = lz - q1.y;
    d2 = dx * dx + dy * dy + dz * dz; m = fminf(m, d2);
    dx = lx - q1.z; dy = ly - q1.w; dz = lz - q2.x;
    d2 = dx * dx + dy * dy + dz * dz; m = fminf(m, d2);
    dx = lx - q2.y; dy = ly - q2.z; dz = lz - q2.w;
    d2 = dx * dx + dy * dy + dz * dz; m = fminf(m, d2);
  }
  d2s[tid] = m;
  ysP[tid] = ysum[b * 256 + tid] * (1.f / (float)PP_);
  ysL[tid] = ysum[32768 + b * 256 + tid] * (1.f / (float)LP_);
  __syncthreads();

  if (tid < 128) {
    float dmin = sqrtf(fminf(d2s[tid], d2s[tid + 128]));
    float s = dmin, mn = dmin;
#pragma unroll
    for (int off = 32; off; off >>= 1) {
      s += __shfl_down(s, off);
      mn = fminf(mn, __shfl_down(mn, off));
    }
    if ((tid & 63) == 0) { red[(tid >> 6) * 2] = s; red[(tid >> 6) * 2 + 1] = mn; }
  }
  __syncthreads();
  if (tid == 0) {
    gf[512] = (red[0] + red[2]) * (1.f / (float)LP_);
    gf[513] = fminf(red[1], red[3]);
  }

  // --- pooled GEMM2 (fp32): thread = output col
  float aP = 0.f, aL = 0.f;
#pragma unroll 8
  for (int k = 0; k < 256; ++k) {
    float w = W2[k * 256 + tid];
    aP += ysP[k] * w;
    aL += ysL[k] * w;
  }
  gf[tid] = aP + bd2[tid];
  gf[256 + tid] = aL + bd2[tid];
  __syncthreads();

  // --- affinity head
  float a = ba1[tid];
#pragma unroll 8
  for (int i = 0; i < 514; ++i) a += gf[i] * Wa1[i * 256 + tid];
  float s = a * __builtin_amdgcn_rcpf(1.f + __expf(-a));
  float p = s * Wa2[tid];
#pragma unroll
  for (int off = 32; off; off >>= 1) p += __shfl_down(p, off);
  __syncthreads();
  if ((tid & 63) == 0) red[tid >> 6] = p;
  __syncthreads();
  if (tid == 0) out[b] = red[0] + red[1] + red[2] + red[3] + ba2[0];
}

// ---------------------------------------------------------------- launch
extern "C" void kernel_launch(void* const* d_in, const int* in_sizes, int n_in,
                              void* d_out, int out_size, void* d_ws, size_t ws_size,
                              hipStream_t stream)
{
  const float* protein_pos = (const float*)d_in[0];
  const float* ligand_pos  = (const float*)d_in[1];
  const int*   pel  = (const int*)d_in[2];
  const int*   paa  = (const int*)d_in[3];
  const int*   pbb  = (const int*)d_in[4];
  const int*   ltyp = (const int*)d_in[5];
  const float* Ee  = (const float*)d_in[8];
  const float* Ea  = (const float*)d_in[9];
  const float* Eb  = (const float*)d_in[10];
  const float* El  = (const float*)d_in[11];
  const float* Wd1 = (const float*)d_in[12];
  const float* bd1 = (const float*)d_in[13];
  const float* Wd2 = (const float*)d_in[14];
  const float* bd2 = (const float*)d_in[15];
  const float* Wa1 = (const float*)d_in[16];
  const float* ba1 = (const float*)d_in[17];
  const float* Wa2 = (const float*)d_in[18];
  const float* ba2 = (const float*)d_in[19];
  float* out = (float*)d_out;

  char* ws = (char*)d_ws;
  f16*   w1t  = (f16*)(ws);                 // 65536 f16 = 131072 B
  f16*   tbl  = (f16*)(ws + 131072);        // 45568 f16 = 91136 B
  float* ysum = (float*)(ws + 262144);      // 65536 f32 = 262144 B (P pools | L pools)

  prep_k<<<256, 256, 0, stream>>>(Wd1, Ee, Ea, Eb, El, w1t, tbl, ysum);
  mlp1pool_k<<<GRID_MLP, 256, 0, stream>>>(pel, paa, pbb, ltyp, tbl, w1t, bd1, ysum);
  final_k<<<B_, 256, 0, stream>>>(protein_pos, ligand_pos, ysum, Wd2, bd2,
                                  Wa1, ba1, Wa2, ba2, out);
}

// Round 3
// 158.909 us; speedup vs baseline: 2.1371x; 1.2018x over previous
//
#include <hip/hip_runtime.h>
#include <hip/hip_bf16.h>

typedef unsigned short u16;
typedef _Float16 f16;
typedef _Float16 h8 __attribute__((ext_vector_type(8)));
typedef float f32x4 __attribute__((ext_vector_type(4)));

#define B_   128
#define PP_  1024
#define LP_  128
#define H_   256
#define NP_  131072
#define NL_  16384
#define NT_  4608      // (131072 + 16384) / 32 row-tiles
#define GRID_MLP 512
#define ASTRIDE 264    // 256 + 8 pad (f16 units)

// ---------------------------------------------------------------- prep
// grid 256: every block zeros its slice of ysum; blocks 0..63 transpose
// W1 -> f16 w1t[n*256+k]; blocks 64..241 convert embedding tables to f16.
__global__ void __launch_bounds__(256) prep_k(
    const float* __restrict__ W1,
    const float* __restrict__ Ee, const float* __restrict__ Ea,
    const float* __restrict__ Eb, const float* __restrict__ El,
    f16* __restrict__ w1t, f16* __restrict__ tbl, float* __restrict__ ysum)
{
  __shared__ float t1[32][33];
  const int bid = blockIdx.x, tid = threadIdx.x;
  ysum[bid * 256 + tid] = 0.f;
  if (bid < 64) {
    const int bx = (bid & 7) * 32, by = (bid >> 3) * 32;
    const int lx = tid & 31, ly = tid >> 5;
#pragma unroll
    for (int r = 0; r < 32; r += 8)
      t1[ly + r][lx] = W1[(by + ly + r) * 256 + bx + lx];
    __syncthreads();
#pragma unroll
    for (int r = 0; r < 32; r += 8)
      w1t[(bx + ly + r) * 256 + by + lx] = (f16)t1[lx][ly + r];
  } else if (bid < 242) {
    const int idx = (bid - 64) * 256 + tid;   // 178 blocks cover exactly 45568
    float v;
    if (idx < 32768)      v = Ee[idx];
    else if (idx < 40960) v = Ea[idx - 32768];
    else if (idx < 41472) v = Eb[idx - 40960];
    else                  v = El[idx - 41472];
    tbl[idx] = (f16)v;
  }
}

// ---------------------------------------------------------------- prep2
// Collapse Wd2@Wa1 (no nonlinearity between them; pooling is linear):
//   WcP[c][j] = (1/PP) sum_n Wd2[c][n] Wa1[n][j]
//   WcL[c][j] = (1/LP) sum_n Wd2[c][n] Wa1[256+n][j]
//   cvec[j]   = sum_n bd2[n] (Wa1[n][j] + Wa1[256+n][j]) + ba1[j]
// grid 257 x 256.
__global__ void __launch_bounds__(256) prep2_k(
    const float* __restrict__ W2, const float* __restrict__ Wa1,
    const float* __restrict__ ba1, const float* __restrict__ bd2,
    float* __restrict__ wc, float* __restrict__ cvec)
{
  __shared__ float wrow[256];
  const int bid = blockIdx.x, tid = threadIdx.x;
  if (bid < 256) {
    wrow[tid] = W2[bid * 256 + tid];
    __syncthreads();
    float aP0 = 0.f, aP1 = 0.f, aL0 = 0.f, aL1 = 0.f;
#pragma unroll 4
    for (int n = 0; n < 256; n += 2) {
      float w0 = wrow[n], w1 = wrow[n + 1];
      aP0 += w0 * Wa1[n * 256 + tid];
      aP1 += w1 * Wa1[(n + 1) * 256 + tid];
      aL0 += w0 * Wa1[(256 + n) * 256 + tid];
      aL1 += w1 * Wa1[(257 + n) * 256 + tid];
    }
    wc[bid * 256 + tid]         = (aP0 + aP1) * (1.f / (float)PP_);
    wc[65536 + bid * 256 + tid] = (aL0 + aL1) * (1.f / (float)LP_);
  } else {
    float a = ba1[tid];
#pragma unroll 8
    for (int n = 0; n < 256; ++n)
      a += bd2[n] * (Wa1[n * 256 + tid] + Wa1[(256 + n) * 256 + tid]);
    cvec[tid] = a;
  }
}

// ---------------------------------------------------------------- GEMM1 + silu + batch colsum
// Double-buffered LDS A-tile + register prefetch of tile T+GRID issued before
// the MFMA loop: one barrier per tile, gather latency hidden behind MFMA.
__global__ void __launch_bounds__(256, 2) mlp1pool_k(
    const int* __restrict__ pel, const int* __restrict__ paa,
    const int* __restrict__ pbb, const int* __restrict__ ltyp,
    const f16* __restrict__ tbl, const f16* __restrict__ w1t,
    const float* __restrict__ bd1, float* __restrict__ ysum)
{
  __shared__ __attribute__((aligned(16))) f16 ldsA[2][32 * ASTRIDE];  // 33 KB
  const f16* Te = tbl;
  const f16* Ta = tbl + 32768;
  const f16* Tb = tbl + 40960;
  const f16* Tl = tbl + 41472;

  const int tid = threadIdx.x;
  const int wave = tid >> 6, lane = tid & 63;
  const int l15 = lane & 15, quad = lane >> 4;
  const int n0 = wave * 64;
  const int srow = tid >> 3, scp = tid & 7;  // staging: 8 threads/row, 32 k each

  // resident weights: 32 frags x 16 B = 128 VGPRs
  h8 Breg[32];
#pragma unroll
  for (int t = 0; t < 4; ++t)
#pragma unroll
    for (int ks = 0; ks < 8; ++ks)
      Breg[t * 8 + ks] = *(const h8*)(w1t + (n0 + t * 16 + l15) * 256 + ks * 32 + quad * 8);

  float bias[4];
#pragma unroll
  for (int t = 0; t < 4; ++t) bias[t] = bd1[n0 + t * 16 + l15];

  f32x4 acc[8];
#pragma unroll
  for (int i = 0; i < 8; ++i) acc[i] = (f32x4){0.f, 0.f, 0.f, 0.f};

  auto fetchv = [&](int T, h8* v) {
    if (T < 4096) {
      const int grow = T * 32 + srow;
      const h8* s0 = (const h8*)(Te + pel[grow] * 256 + scp * 32);
      const h8* s1 = (const h8*)(Ta + paa[grow] * 256 + scp * 32);
      const h8* s2 = (const h8*)(Tb + pbb[grow] * 256 + scp * 32);
#pragma unroll
      for (int c = 0; c < 4; ++c) v[c] = s0[c] + s1[c] + s2[c];
    } else {
      const int lrow = (T - 4096) * 32 + srow;
      const h8* s0 = (const h8*)(Tl + ltyp[lrow] * 256 + scp * 32);
#pragma unroll
      for (int c = 0; c < 4; ++c) v[c] = s0[c];
    }
  };

  h8 v[4];
  fetchv(blockIdx.x, v);
#pragma unroll
  for (int c = 0; c < 4; ++c)
    *(h8*)(ldsA[0] + srow * ASTRIDE + scp * 32 + c * 8) = v[c];

  int buf = 0;
  for (int T = blockIdx.x; T < NT_; T += GRID_MLP, buf ^= 1) {
    const bool prot = T < 4096;
    const int Tn = T + GRID_MLP;
    const bool more = Tn < NT_;
    __syncthreads();   // ldsA[buf] fully staged

    h8 vn[4];
    if (more) fetchv(Tn, vn);   // issue gathers; latency hidden by MFMA below

#pragma unroll
    for (int ks = 0; ks < 8; ++ks) {
      h8 a0 = *(const h8*)(ldsA[buf] + l15 * ASTRIDE + ks * 32 + quad * 8);
      h8 a1 = *(const h8*)(ldsA[buf] + (16 + l15) * ASTRIDE + ks * 32 + quad * 8);
#pragma unroll
      for (int t = 0; t < 4; ++t) {
        acc[t]     = __builtin_amdgcn_mfma_f32_16x16x32_f16(a0, Breg[t * 8 + ks], acc[t], 0, 0, 0);
        acc[4 + t] = __builtin_amdgcn_mfma_f32_16x16x32_f16(a1, Breg[t * 8 + ks], acc[4 + t], 0, 0, 0);
      }
    }

    if (more) {
#pragma unroll
      for (int c = 0; c < 4; ++c)
        *(h8*)(ldsA[buf ^ 1] + srow * ASTRIDE + scp * 32 + c * 8) = vn[c];
    }

    // epilogue: silu + column sum over this tile's 32 rows -> atomic pool add
    const int batch = prot ? (T >> 5) : ((T - 4096) >> 2);
    float* pool = ysum + (prot ? 0 : 32768) + batch * 256;
#pragma unroll
    for (int t = 0; t < 4; ++t) {
      float s = 0.f;
#pragma unroll
      for (int mi = 0; mi < 2; ++mi)
#pragma unroll
        for (int r = 0; r < 4; ++r) {
          float pre = acc[mi * 4 + t][r] + bias[t];
          s += pre * __builtin_amdgcn_rcpf(1.f + __expf(-pre));
        }
      s += __shfl_xor(s, 16);
      s += __shfl_xor(s, 32);
      if (lane < 16) atomicAdd(pool + n0 + t * 16 + lane, s);
      acc[t] = (f32x4){0.f, 0.f, 0.f, 0.f};
      acc[4 + t] = (f32x4){0.f, 0.f, 0.f, 0.f};
    }
  }
}

// ---------------------------------------------------------------- head: contact + collapsed matvec
// One block (512 thr) per batch. Contact from padded LDS (float4, conflict-free).
// pre[j] = ysumP@WcP + ysumL@WcL + cvec + c0*Wa1[512] + c1*Wa1[513];
// out = silu(pre)@Wa2 + ba2. K split across 2 thread-groups, 4 accumulators.
__global__ void __launch_bounds__(512) head_k(
    const float* __restrict__ ppos, const float* __restrict__ lpos,
    const float* __restrict__ ysum, const float* __restrict__ wc,
    const float* __restrict__ cvec, const float* __restrict__ Wa1,
    const float* __restrict__ Wa2, const float* __restrict__ ba2,
    float* __restrict__ out)
{
  __shared__ float px[4 * 264], py[4 * 264], pz[4 * 264];  // 4 segs of 256 + 8 pad
  __shared__ float ysc[512];
  __shared__ float part[512];
  __shared__ float lmin[128];
  __shared__ float cls[2];
  __shared__ float red[4];
  const int b = blockIdx.x, tid = threadIdx.x;

  // stage protein positions (padded segments) + pool sums
#pragma unroll
  for (int r = 0; r < 2; ++r) {
    const int i = r * 512 + tid;            // 0..1023
    const int d = (i >> 8) * 264 + (i & 255);
    const float* p = ppos + ((size_t)b * PP_ + i) * 3;
    px[d] = p[0]; py[d] = p[1]; pz[d] = p[2];
  }
  ysc[tid] = (tid < 256) ? ysum[b * 256 + tid]
                         : ysum[32768 + b * 256 + (tid - 256)];
  __syncthreads();

  // contact: 4 threads per ligand, 256 points each, float4 LDS reads
  {
    const int lig = tid >> 2, prt = tid & 3;
    const float* lp = lpos + ((size_t)b * LP_ + lig) * 3;
    const float lx = lp[0], ly = lp[1], lz = lp[2];
    const float4* X4 = (const float4*)(px + prt * 264);
    const float4* Y4 = (const float4*)(py + prt * 264);
    const float4* Z4 = (const float4*)(pz + prt * 264);
    float m = 3.4e38f;
#pragma unroll 8
    for (int i = 0; i < 64; ++i) {
      float4 X = X4[i], Y = Y4[i], Z = Z4[i];
      float dx, dy, dz, d2;
      dx = lx - X.x; dy = ly - Y.x; dz = lz - Z.x;
      d2 = dx * dx + dy * dy + dz * dz; m = fminf(m, d2);
      dx = lx - X.y; dy = ly - Y.y; dz = lz - Z.y;
      d2 = dx * dx + dy * dy + dz * dz; m = fminf(m, d2);
      dx = lx - X.z; dy = ly - Y.z; dz = lz - Z.z;
      d2 = dx * dx + dy * dy + dz * dz; m = fminf(m, d2);
      dx = lx - X.w; dy = ly - Y.w; dz = lz - Z.w;
      d2 = dx * dx + dy * dy + dz * dz; m = fminf(m, d2);
    }
    m = fminf(m, __shfl_xor(m, 1));
    m = fminf(m, __shfl_xor(m, 2));
    if (prt == 0) lmin[lig] = sqrtf(m);
  }
  __syncthreads();
  if (tid < 64) {
    const float a0 = lmin[tid], a1 = lmin[tid + 64];
    float s = a0 + a1, mn = fminf(a0, a1);
#pragma unroll
    for (int off = 32; off; off >>= 1) {
      s += __shfl_down(s, off);
      mn = fminf(mn, __shfl_down(mn, off));
    }
    if (tid == 0) { cls[0] = s * (1.f / (float)LP_); cls[1] = mn; }
  }

  // matvec partials: group g covers k-half, thread = output col
  {
    const int g = tid >> 8, j = tid & 255;
    const float* W = wc + g * 65536 + j;
    const float* ys = ysc + g * 256;
    float a0 = 0.f, a1 = 0.f, a2 = 0.f, a3 = 0.f;
#pragma unroll 4
    for (int k = 0; k < 256; k += 4) {
      a0 += ys[k]     * W[(k)     * 256];
      a1 += ys[k + 1] * W[(k + 1) * 256];
      a2 += ys[k + 2] * W[(k + 2) * 256];
      a3 += ys[k + 3] * W[(k + 3) * 256];
    }
    part[tid] = (a0 + a1) + (a2 + a3);
  }
  __syncthreads();

  if (tid < 256) {
    float pre = part[tid] + part[256 + tid] + cvec[tid]
              + cls[0] * Wa1[512 * 256 + tid] + cls[1] * Wa1[513 * 256 + tid];
    float s = pre * __builtin_amdgcn_rcpf(1.f + __expf(-pre));
    float p = s * Wa2[tid];
#pragma unroll
    for (int off = 32; off; off >>= 1) p += __shfl_down(p, off);
    if ((tid & 63) == 0) red[tid >> 6] = p;
  }
  __syncthreads();
  if (tid == 0) out[b] = (red[0] + red[1]) + (red[2] + red[3]) + ba2[0];
}

// ---------------------------------------------------------------- launch
extern "C" void kernel_launch(void* const* d_in, const int* in_sizes, int n_in,
                              void* d_out, int out_size, void* d_ws, size_t ws_size,
                              hipStream_t stream)
{
  const float* protein_pos = (const float*)d_in[0];
  const float* ligand_pos  = (const float*)d_in[1];
  const int*   pel  = (const int*)d_in[2];
  const int*   paa  = (const int*)d_in[3];
  const int*   pbb  = (const int*)d_in[4];
  const int*   ltyp = (const int*)d_in[5];
  const float* Ee  = (const float*)d_in[8];
  const float* Ea  = (const float*)d_in[9];
  const float* Eb  = (const float*)d_in[10];
  const float* El  = (const float*)d_in[11];
  const float* Wd1 = (const float*)d_in[12];
  const float* bd1 = (const float*)d_in[13];
  const float* Wd2 = (const float*)d_in[14];
  const float* bd2 = (const float*)d_in[15];
  const float* Wa1 = (const float*)d_in[16];
  const float* ba1 = (const float*)d_in[17];
  const float* Wa2 = (const float*)d_in[18];
  const float* ba2 = (const float*)d_in[19];
  float* out = (float*)d_out;

  char* ws = (char*)d_ws;
  f16*   w1t  = (f16*)(ws);                  // 131072 B
  f16*   tbl  = (f16*)(ws + 131072);         // 91136 B
  float* ysum = (float*)(ws + 262144);       // 262144 B (P pools | L pools)
  float* wc   = (float*)(ws + 524288);       // 524288 B (WcP | WcL)
  float* cvec = (float*)(ws + 1048576);      // 1024 B

  prep_k<<<256, 256, 0, stream>>>(Wd1, Ee, Ea, Eb, El, w1t, tbl, ysum);
  prep2_k<<<257, 256, 0, stream>>>(Wd2, Wa1, ba1, bd2, wc, cvec);
  mlp1pool_k<<<GRID_MLP, 256, 0, stream>>>(pel, paa, pbb, ltyp, tbl, w1t, bd1, ysum);
  head_k<<<B_, 512, 0, stream>>>(protein_pos, ligand_pos, ysum, wc, cvec,
                                 Wa1, Wa2, ba2, out);
}